// Round 1
// baseline (1247.351 us; speedup 1.0000x reference)
//
#include <hip/hip_runtime.h>
#include <hip/hip_bf16.h>
#include <stdint.h>

#define Dm 1024
#define MT 32768
#define NLAYER 6

typedef __attribute__((ext_vector_type(8))) short bfvec8;
typedef __attribute__((ext_vector_type(4))) float fvec4;

__device__ __forceinline__ float bf2f(unsigned short u){
    union { unsigned int i; float f; } v; v.i = ((unsigned int)u) << 16; return v.f;
}
__device__ __forceinline__ unsigned short f2bf(float f){
    union { float f; unsigned int i; } v; v.f = f;
    unsigned int x = v.i;
    return (unsigned short)((x + 0x7fffu + ((x >> 16) & 1u)) >> 16);
}

__device__ __forceinline__ void gload_lds16(const void* g, void* lds){
    __builtin_amdgcn_global_load_lds(
        (const __attribute__((address_space(1))) void*)(uintptr_t)g,
        (__attribute__((address_space(3))) void*)(unsigned int)(uintptr_t)lds,
        16, 0, 0);
}

// ---- W' = dequant(q, scale) + lb @ la  (LoRA folded into the weight), bf16 out.
// One block = one layer l, 8 output rows, all 1024 cols. lb rows cached in LDS,
// la read as float4 per rank (coalesced, L2-resident: 128 KB/layer).
__global__ __launch_bounds__(256) void prep_w2(const int* __restrict__ q,
                                               const float* __restrict__ sc,
                                               const float* __restrict__ la,
                                               const float* __restrict__ lb,
                                               unsigned short* __restrict__ wbf){
    __shared__ float lbs[256];                  // lb[og..og+7][0..31]
    const int tid = threadIdx.x;
    const int l  = blockIdx.x >> 7;             // 128 blocks per layer
    const int og = (blockIdx.x & 127) * 8;
    lbs[tid] = lb[(size_t)l * Dm * 32 + og * 32 + tid];
    __syncthreads();
    const int k0 = tid * 4;
    float acc[8][4] = {};
    const float* lal = la + (size_t)l * 32 * Dm + k0;
    #pragma unroll 4
    for (int r = 0; r < 32; r++) {
        float4 v = *(const float4*)(lal + (size_t)r * Dm);
        #pragma unroll
        for (int i = 0; i < 8; i++) {
            float c = lbs[i * 32 + r];
            acc[i][0] = fmaf(c, v.x, acc[i][0]);
            acc[i][1] = fmaf(c, v.y, acc[i][1]);
            acc[i][2] = fmaf(c, v.z, acc[i][2]);
            acc[i][3] = fmaf(c, v.w, acc[i][3]);
        }
    }
    #pragma unroll
    for (int i = 0; i < 8; i++) {
        const size_t row = (size_t)l * Dm + og + i;
        int4 qv = *(const int4*)(q + row * Dm + k0);
        float s  = sc[row * (Dm / 16) + (k0 >> 4)];
        float si = s * (1.0f / 7.5f);
        // (q/7.5 - 1)*s + acc  ==  q*si + (acc - s)
        ushort4 o;
        o.x = f2bf(fmaf((float)qv.x, si, acc[i][0] - s));
        o.y = f2bf(fmaf((float)qv.y, si, acc[i][1] - s));
        o.z = f2bf(fmaf((float)qv.z, si, acc[i][2] - s));
        o.w = f2bf(fmaf((float)qv.w, si, acc[i][3] - s));
        *(ushort4*)(wbf + row * Dm + k0) = o;
    }
}

// ---- fp32 -> bf16 convert (n multiple of 1024)
__global__ __launch_bounds__(256) void conv_bf16_kernel(const float* __restrict__ in,
                                                        unsigned short* __restrict__ out){
    size_t i = ((size_t)blockIdx.x * 256 + threadIdx.x) * 4;
    float4 v = *(const float4*)(in + i);
    ushort4 o;
    o.x = f2bf(v.x); o.y = f2bf(v.y); o.z = f2bf(v.z); o.w = f2bf(v.w);
    *(ushort4*)(out + i) = o;
}

// ---- main GEMM: C[m,n] = sum_k A[m,k]*W[n,k] + bias[n] (+resid)
// 128x128 tile, BK=64, SINGLE-buffered 32 KB LDS (-> 4 blocks/CU with
// __launch_bounds__(256,4); was 2 blocks/CU at 64 KB). Per K-iter:
// stage -> sync(drain) -> compute -> sync. Cross-block overlap hides the drain.
// LoRA is pre-folded into W, so no tail. Epilogue transposes C through the same
// 32 KB LDS in two 64x128 half-passes for coalesced float4 resid/out traffic.
__global__ __launch_bounds__(256, 4) void qlora_gemm(
    const unsigned short* __restrict__ A,
    const unsigned short* __restrict__ W,
    const float* __restrict__ bias,
    const float* __restrict__ resid,
    float* __restrict__ outf,
    unsigned short* __restrict__ outb)
{
    __shared__ char smem[32768];
    unsigned short* As = (unsigned short*)smem;             // [128*64]
    unsigned short* Ws = (unsigned short*)(smem + 16384);   // [128*64]
    float* Cs = (float*)smem;                               // epilogue reuse [64][128]

    const int tid = threadIdx.x;
    const int wave = tid >> 6, lane = tid & 63;
    const int quad = lane >> 4, l16 = lane & 15;
    const int wm = wave >> 1, wn = wave & 1;

    const int bid = blockIdx.x;                 // 2048 blocks
    const int within = bid & 63;                // 8m x 8n supertile band
    const int band = bid >> 6;
    const int m0 = (band * 8 + (within & 7)) * 128;
    const int n0 = (within >> 3) * 128;

    const int r8 = tid >> 3;                            // 0..31: row within pass
    const int o8 = (((tid & 7) ^ (r8 & 7)) * 8);        // swizzled source granule

    fvec4 acc[4][4] = {};

    // stage one 128x64 A-tile + W-tile (pre-swizzled global src, linear LDS dest)
    auto stage = [&](int k0) {
        #pragma unroll
        for (int p = 0; p < 4; p++) {
            int row = p * 32 + r8;
            gload_lds16(A + (size_t)(m0 + row) * Dm + k0 + o8,
                        (char*)As + (p * 256 + wave * 64) * 16);
            gload_lds16(W + (size_t)(n0 + row) * Dm + k0 + o8,
                        (char*)Ws + (p * 256 + wave * 64) * 16);
        }
    };

    #pragma unroll 2
    for (int k0 = 0; k0 < Dm; k0 += 64) {
        stage(k0);
        __syncthreads();                 // vmcnt(0) drain: this tile's loads done
        #pragma unroll
        for (int ks = 0; ks < 64; ks += 32) {
            const int s = (((ks >> 3) + quad) ^ (l16 & 7)) * 8;
            bfvec8 af[4], bw[4];
            #pragma unroll
            for (int i = 0; i < 4; i++) {
                af[i] = *(const bfvec8*)(As + (wm * 64 + i * 16 + l16) * 64 + s);
                bw[i] = *(const bfvec8*)(Ws + (wn * 64 + i * 16 + l16) * 64 + s);
            }
            #pragma unroll
            for (int mi = 0; mi < 4; mi++)
                #pragma unroll
                for (int ni = 0; ni < 4; ni++)
                    acc[mi][ni] = __builtin_amdgcn_mfma_f32_16x16x32_bf16(af[mi], bw[ni], acc[mi][ni], 0, 0, 0);
        }
        __syncthreads();                 // reads done before next stage overwrites
    }

    // ---- epilogue: two 64x128 half-passes through the 32 KB LDS
    #pragma unroll
    for (int h = 0; h < 2; h++) {
        if (h) __syncthreads();          // pass-0 reads done before pass-1 writes
        if (wm == h) {
            #pragma unroll
            for (int mi = 0; mi < 4; mi++)
                #pragma unroll
                for (int ni = 0; ni < 4; ni++)
                    #pragma unroll
                    for (int r = 0; r < 4; r++)
                        Cs[(mi * 16 + quad * 4 + r) * 128 + (wn * 64 + ni * 16 + l16)] = acc[mi][ni][r];
        }
        __syncthreads();
        #pragma unroll
        for (int j = 0; j < 8; j++) {
            const int idx = j * 256 + tid;       // float4 index over 64x32
            const int row = idx >> 5;
            const int c4  = (idx & 31) * 4;
            float4 v = ((const float4*)Cs)[idx];
            float4 bv = *(const float4*)(bias + n0 + c4);
            v.x += bv.x; v.y += bv.y; v.z += bv.z; v.w += bv.w;
            const size_t off = (size_t)(m0 + h * 64 + row) * Dm + n0 + c4;
            if (resid) {
                float4 rv = *(const float4*)(resid + off);
                v.x += rv.x; v.y += rv.y; v.z += rv.z; v.w += rv.w;
            }
            if (outf) *(float4*)(outf + off) = v;
            if (outb) {
                ushort4 o;
                o.x = f2bf(v.x); o.y = f2bf(v.y); o.z = f2bf(v.z); o.w = f2bf(v.w);
                *(ushort4*)(outb + off) = o;
            }
        }
    }
}

// ---- fast exact GELU: erf via Abramowitz-Stegun 7.1.26 (|err| <= 1.5e-7)
__device__ __forceinline__ float gelu_exact(float z){
    float a = fabsf(z) * 0.70710678118654752f;
    float t = 1.0f / fmaf(0.3275911f, a, 1.0f);
    float p = t * fmaf(t, fmaf(t, fmaf(t, fmaf(t, 1.061405429f, -1.453152027f),
                                       1.421413741f), -0.284496736f), 0.254829592f);
    float e = __expf(-a * a);
    float erfa = copysignf(fmaf(-p, e, 1.0f), z);
    return 0.5f * z * (1.0f + erfa);
}

// ---- LayerNorm + GELU over rows of 1024, one block per row
__global__ __launch_bounds__(256) void ln_gelu_kernel(const unsigned short* __restrict__ Y,
                                                      const float* __restrict__ g,
                                                      const float* __restrict__ b,
                                                      unsigned short* __restrict__ Aout){
    const int row = blockIdx.x;
    const int tid = threadIdx.x;
    const unsigned short* yr = Y + (size_t)row * Dm;
    ushort4 u = *(const ushort4*)(yr + tid * 4);
    float x0 = bf2f(u.x), x1 = bf2f(u.y), x2 = bf2f(u.z), x3 = bf2f(u.w);
    float s  = x0 + x1 + x2 + x3;
    float ss = x0 * x0 + x1 * x1 + x2 * x2 + x3 * x3;
    #pragma unroll
    for (int d = 32; d > 0; d >>= 1) {
        s  += __shfl_down(s, d);
        ss += __shfl_down(ss, d);
    }
    __shared__ float sb[8];
    const int wave = tid >> 6, lane = tid & 63;
    if (lane == 0) { sb[wave] = s; sb[4 + wave] = ss; }
    __syncthreads();
    s  = sb[0] + sb[1] + sb[2] + sb[3];
    ss = sb[4] + sb[5] + sb[6] + sb[7];
    const float mu = s * (1.0f / Dm);
    const float var = ss * (1.0f / Dm) - mu * mu;
    const float rstd = rsqrtf(var + 1e-5f);
    float4 gv = *(const float4*)(g + tid * 4);
    float4 bv = *(const float4*)(b + tid * 4);
    float z0 = (x0 - mu) * rstd * gv.x + bv.x;
    float z1 = (x1 - mu) * rstd * gv.y + bv.y;
    float z2 = (x2 - mu) * rstd * gv.z + bv.z;
    float z3 = (x3 - mu) * rstd * gv.w + bv.w;
    ushort4 o;
    o.x = f2bf(gelu_exact(z0)); o.y = f2bf(gelu_exact(z1));
    o.z = f2bf(gelu_exact(z2)); o.w = f2bf(gelu_exact(z3));
    *(ushort4*)(Aout + (size_t)row * Dm + tid * 4) = o;
}

extern "C" void kernel_launch(void* const* d_in, const int* in_sizes, int n_in,
                              void* d_out, int out_size, void* d_ws, size_t ws_size,
                              hipStream_t stream) {
    (void)in_sizes; (void)n_in; (void)out_size; (void)ws_size;
    const float* x   = (const float*)d_in[0];
    const int*   qw  = (const int*)d_in[1];
    const float* sc  = (const float*)d_in[2];
    const float* bia = (const float*)d_in[3];
    const float* la  = (const float*)d_in[4];
    const float* lb  = (const float*)d_in[5];
    const float* gam = (const float*)d_in[6];
    const float* bet = (const float*)d_in[7];
    float* out = (float*)d_out;

    char* p = (char*)d_ws;
    unsigned short* Wbf = (unsigned short*)p; p += (size_t)NLAYER * Dm * Dm * 2;
    unsigned short* Pb  = (unsigned short*)p; p += (size_t)MT * Dm * 2;
    unsigned short* Qb  = (unsigned short*)p; p += (size_t)MT * Dm * 2;

    prep_w2<<<NLAYER * Dm / 8, 256, 0, stream>>>(qw, sc, la, lb, Wbf);
    conv_bf16_kernel<<<MT * (Dm / 4) / 256, 256, 0, stream>>>(x, Pb);

    unsigned short *curP = Pb, *curQ = Qb;
    for (int blk = 0; blk < 3; blk++) {
        int i0 = 2 * blk, i1 = i0 + 1;
        qlora_gemm<<<2048, 256, 0, stream>>>(
            curP, Wbf + (size_t)i0 * Dm * Dm,
            bia + i0 * Dm, nullptr, nullptr, curQ);
        ln_gelu_kernel<<<MT, 256, 0, stream>>>(curQ, gam + blk * Dm, bet + blk * Dm, curP);
        qlora_gemm<<<2048, 256, 0, stream>>>(
            curP, Wbf + (size_t)i1 * Dm * Dm,
            bia + i1 * Dm, blk == 0 ? x : (const float*)out, out,
            blk == 2 ? nullptr : curQ);
        unsigned short* t = curP; curP = curQ; curQ = t;
    }
}

// Round 2
// 927.839 us; speedup vs baseline: 1.3444x; 1.3444x over previous
//
#include <hip/hip_runtime.h>
#include <hip/hip_bf16.h>
#include <stdint.h>

#define Dm 1024
#define MT 32768
#define NLAYER 6

typedef __attribute__((ext_vector_type(8))) short bfvec8;
typedef __attribute__((ext_vector_type(4))) float fvec4;

__device__ __forceinline__ float bf2f(unsigned short u){
    union { unsigned int i; float f; } v; v.i = ((unsigned int)u) << 16; return v.f;
}
__device__ __forceinline__ unsigned short f2bf(float f){
    union { float f; unsigned int i; } v; v.f = f;
    unsigned int x = v.i;
    return (unsigned short)((x + 0x7fffu + ((x >> 16) & 1u)) >> 16);
}

__device__ __forceinline__ void gload_lds16(const void* g, void* lds){
    __builtin_amdgcn_global_load_lds(
        (const __attribute__((address_space(1))) void*)(uintptr_t)g,
        (__attribute__((address_space(3))) void*)(unsigned int)(uintptr_t)lds,
        16, 0, 0);
}

#define BAR1() asm volatile("s_waitcnt lgkmcnt(0)\n\ts_barrier" ::: "memory")
#define BAR2() asm volatile("s_barrier" ::: "memory")
#define WAIT_VM6() asm volatile("s_waitcnt vmcnt(6)" ::: "memory")
#define WAIT_VM0() asm volatile("s_waitcnt vmcnt(0)" ::: "memory")

// ---- W' = dequant(q, scale) + lb @ la  (LoRA folded into the weight), bf16 out.
__global__ __launch_bounds__(256) void prep_w2(const int* __restrict__ q,
                                               const float* __restrict__ sc,
                                               const float* __restrict__ la,
                                               const float* __restrict__ lb,
                                               unsigned short* __restrict__ wbf){
    __shared__ float lbs[256];                  // lb[og..og+7][0..31]
    const int tid = threadIdx.x;
    const int l  = blockIdx.x >> 7;             // 128 blocks per layer
    const int og = (blockIdx.x & 127) * 8;
    lbs[tid] = lb[(size_t)l * Dm * 32 + og * 32 + tid];
    __syncthreads();
    const int k0 = tid * 4;
    float acc[8][4] = {};
    const float* lal = la + (size_t)l * 32 * Dm + k0;
    #pragma unroll 4
    for (int r = 0; r < 32; r++) {
        float4 v = *(const float4*)(lal + (size_t)r * Dm);
        #pragma unroll
        for (int i = 0; i < 8; i++) {
            float c = lbs[i * 32 + r];
            acc[i][0] = fmaf(c, v.x, acc[i][0]);
            acc[i][1] = fmaf(c, v.y, acc[i][1]);
            acc[i][2] = fmaf(c, v.z, acc[i][2]);
            acc[i][3] = fmaf(c, v.w, acc[i][3]);
        }
    }
    #pragma unroll
    for (int i = 0; i < 8; i++) {
        const size_t row = (size_t)l * Dm + og + i;
        int4 qv = *(const int4*)(q + row * Dm + k0);
        float s  = sc[row * (Dm / 16) + (k0 >> 4)];
        float si = s * (1.0f / 7.5f);
        ushort4 o;
        o.x = f2bf(fmaf((float)qv.x, si, acc[i][0] - s));
        o.y = f2bf(fmaf((float)qv.y, si, acc[i][1] - s));
        o.z = f2bf(fmaf((float)qv.z, si, acc[i][2] - s));
        o.w = f2bf(fmaf((float)qv.w, si, acc[i][3] - s));
        *(ushort4*)(wbf + row * Dm + k0) = o;
    }
}

// ---- fp32 -> bf16 convert (n multiple of 1024)
__global__ __launch_bounds__(256) void conv_bf16_kernel(const float* __restrict__ in,
                                                        unsigned short* __restrict__ out){
    size_t i = ((size_t)blockIdx.x * 256 + threadIdx.x) * 4;
    float4 v = *(const float4*)(in + i);
    ushort4 o;
    o.x = f2bf(v.x); o.y = f2bf(v.y); o.z = f2bf(v.z); o.w = f2bf(v.w);
    *(ushort4*)(out + i) = o;
}

// ---- main GEMM: C[m,n] = sum_k A[m,k]*W[n,k] + bias[n] (+resid)
// 8-phase 256x256 template (T2+T3+T4+T5): BK=64, 512 thr (8 waves, 2Mx4N),
// 128 KB LDS dbuf. 16 K-tiles = 8 macro-iters x 8 phases. Per phase:
// {ds_read frags || issue 2 global_load_lds} -> lgkm0+barrier -> setprio1,
// 16 MFMA, setprio0 -> barrier. vmcnt(6) only at phases 3 & 7 (counted, never
// 0 in-loop): 3 half-tile stages stay in flight across barriers.
__global__ __launch_bounds__(512, 2) void qlora_gemm(
    const unsigned short* __restrict__ A,
    const unsigned short* __restrict__ W,
    const float* __restrict__ bias,
    const float* __restrict__ resid,
    float* __restrict__ outf,
    unsigned short* __restrict__ outb)
{
    __shared__ char smem[131072];
    unsigned short* As = (unsigned short*)smem;             // [2][256][64]
    unsigned short* Bs = (unsigned short*)(smem + 65536);   // [2][256][64]

    const int tid = threadIdx.x;
    const int wave = tid >> 6, lane = tid & 63;
    const int quad = lane >> 4, l16 = lane & 15;
    const int wm = wave >> 2, wn = wave & 3;    // 2 x 4 wave grid

    // bijective XCD swizzle (512 % 8 == 0): XCD x gets 16 consecutive m-tiles
    // x all 4 n-tiles -> A-band reuse within one XCD's private L2.
    const int wg = (blockIdx.x & 7) * 64 + (blockIdx.x >> 3);
    const int m0 = (wg >> 2) * 256;
    const int n0 = (wg & 3) * 256;

    const int oswz = (((tid & 7) ^ ((tid >> 3) & 7)) * 8);  // source granule swizzle
    const unsigned short* Ag = A + (size_t)m0 * Dm;
    const unsigned short* Wg = W + (size_t)n0 * Dm;

    fvec4 acc[8][4] = {};

    // one stage pass = 64 rows x 64 cols bf16 (512 thr x 16 B), linear LDS dest
    auto stA = [&](int b, int kt, int r0){
        gload_lds16(Ag + (size_t)(r0 + (tid >> 3)) * Dm + kt + oswz,
                    smem + b * 32768 + r0 * 128 + tid * 16);
    };
    auto stB = [&](int b, int kt, int r0){
        gload_lds16(Wg + (size_t)(r0 + (tid >> 3)) * Dm + kt + oswz,
                    smem + 65536 + b * 32768 + r0 * 128 + tid * 16);
    };
    auto ldsA = [&](int b, int pm, int ks, bfvec8* af){
        #pragma unroll
        for (int i = 0; i < 4; i++)
            af[i] = *(const bfvec8*)(As + b * 16384 +
                     (wm * 128 + pm * 64 + i * 16 + l16) * 64 + (((ks * 4 + quad) ^ (l16 & 7)) * 8));
    };
    auto ldsB = [&](int b, int ks, bfvec8* bw){
        #pragma unroll
        for (int n = 0; n < 4; n++)
            bw[n] = *(const bfvec8*)(Bs + b * 16384 +
                     (wn * 64 + n * 16 + l16) * 64 + (((ks * 4 + quad) ^ (l16 & 7)) * 8));
    };
    auto mma = [&](int pm, bfvec8* af, bfvec8* bw){
        __builtin_amdgcn_s_setprio(1);
        #pragma unroll
        for (int i = 0; i < 4; i++)
            #pragma unroll
            for (int n = 0; n < 4; n++)
                acc[pm * 4 + i][n] = __builtin_amdgcn_mfma_f32_16x16x32_bf16(af[i], bw[n], acc[pm * 4 + i][n], 0, 0, 0);
        __builtin_amdgcn_s_setprio(0);
    };

    // prologue: tile0 -> buf0 (8 passes), tile1 -> buf1 (B all + A chunks 0,2)
    stB(0, 0, 0); stB(0, 0, 64); stB(0, 0, 128); stB(0, 0, 192);
    stA(0, 0, 0); stA(0, 0, 64); stA(0, 0, 128); stA(0, 0, 192);
    stB(1, 64, 0); stB(1, 64, 64); stB(1, 64, 128); stB(1, 64, 192);
    stA(1, 64, 0); stA(1, 64, 128);
    asm volatile("s_waitcnt vmcnt(6)\n\ts_barrier" ::: "memory");  // tile0 landed; tile1's 6 in flight

    bfvec8 b0[4], b1[4], af[4];
    #pragma unroll 1
    for (int i = 0; i < 8; i++) {
        const int t1k = (2 * i + 1) * 64;   // buf1's current tile (A chunks 1,3 staged at P0)
        const int s0k = (2 * i + 2) * 64;   // next buf0 tile
        const int s1k = (2 * i + 3) * 64;   // next buf1 tile
        const bool st = (i < 7);

        // P0: compute buf0 (pm0,ks0); read all B + af; stage buf1.A1,A3 of t1
        ldsB(0, 0, b0); ldsB(0, 1, b1); ldsA(0, 0, 0, af);
        stA(1, t1k, 64); stA(1, t1k, 192);
        BAR1(); mma(0, af, b0); BAR2();

        // P1: (pm0,ks1); stage buf0.B0,B1 of s0
        ldsA(0, 0, 1, af);
        if (st) { stB(0, s0k, 0); stB(0, s0k, 64); }
        BAR1(); mma(0, af, b1); BAR2();

        // P2: (pm1,ks0); stage buf0.B2,B3
        ldsA(0, 1, 0, af);
        if (st) { stB(0, s0k, 128); stB(0, s0k, 192); }
        BAR1(); mma(1, af, b0); BAR2();

        // P3: (pm1,ks1); stage buf0.A0,A2; vmcnt checkpoint (t1 fully landed)
        ldsA(0, 1, 1, af);
        if (st) { stA(0, s0k, 0); stA(0, s0k, 128); WAIT_VM6(); }
        else    { WAIT_VM0(); }
        BAR1(); mma(1, af, b1); BAR2();

        // P4: compute buf1 (pm0,ks0); read all B + af; stage buf0.A1,A3 of s0
        ldsB(1, 0, b0); ldsB(1, 1, b1); ldsA(1, 0, 0, af);
        if (st) { stA(0, s0k, 64); stA(0, s0k, 192); }
        BAR1(); mma(0, af, b0); BAR2();

        // P5: (pm0,ks1); stage buf1.B0,B1 of s1
        ldsA(1, 0, 1, af);
        if (st) { stB(1, s1k, 0); stB(1, s1k, 64); }
        BAR1(); mma(0, af, b1); BAR2();

        // P6: (pm1,ks0); stage buf1.B2,B3
        ldsA(1, 1, 0, af);
        if (st) { stB(1, s1k, 128); stB(1, s1k, 192); }
        BAR1(); mma(1, af, b0); BAR2();

        // P7: (pm1,ks1); stage buf1.A0,A2 of s1; vmcnt checkpoint (s0 fully landed)
        ldsA(1, 1, 1, af);
        if (st) { stA(1, s1k, 0); stA(1, s1k, 128); WAIT_VM6(); }
        BAR1(); mma(1, af, b1); BAR2();
    }

    // ---- epilogue: 4 passes of 64 rows through LDS (fp32, stride 260 to
    // de-conflict quad-strided writes), coalesced float4 global traffic.
    float* Cs = (float*)smem;
    #pragma unroll
    for (int h = 0; h < 4; h++) {
        if (h) __syncthreads();          // previous pass reads done
        if (wm == (h >> 1)) {
            #pragma unroll
            for (int ii = 0; ii < 4; ii++)
                #pragma unroll
                for (int n = 0; n < 4; n++)
                    #pragma unroll
                    for (int r = 0; r < 4; r++)
                        Cs[(ii * 16 + quad * 4 + r) * 260 + wn * 64 + n * 16 + l16] =
                            acc[(h & 1) * 4 + ii][n][r];
        }
        __syncthreads();
        #pragma unroll
        for (int j = 0; j < 8; j++) {
            const int idx = j * 512 + tid;       // float4 index over 64x64
            const int rl = idx >> 6;
            const int c4 = (idx & 63) * 4;
            float4 v = *(const float4*)(Cs + rl * 260 + c4);
            float4 bv = *(const float4*)(bias + n0 + c4);
            v.x += bv.x; v.y += bv.y; v.z += bv.z; v.w += bv.w;
            const size_t off = (size_t)(m0 + h * 64 + rl) * Dm + n0 + c4;
            if (resid) {
                float4 rv = *(const float4*)(resid + off);
                v.x += rv.x; v.y += rv.y; v.z += rv.z; v.w += rv.w;
            }
            if (outf) *(float4*)(outf + off) = v;
            if (outb) {
                ushort4 o;
                o.x = f2bf(v.x); o.y = f2bf(v.y); o.z = f2bf(v.z); o.w = f2bf(v.w);
                *(ushort4*)(outb + off) = o;
            }
        }
    }
}

// ---- fast exact GELU: erf via Abramowitz-Stegun 7.1.26 (|err| <= 1.5e-7)
__device__ __forceinline__ float gelu_exact(float z){
    float a = fabsf(z) * 0.70710678118654752f;
    float t = 1.0f / fmaf(0.3275911f, a, 1.0f);
    float p = t * fmaf(t, fmaf(t, fmaf(t, fmaf(t, 1.061405429f, -1.453152027f),
                                       1.421413741f), -0.284496736f), 0.254829592f);
    float e = __expf(-a * a);
    float erfa = copysignf(fmaf(-p, e, 1.0f), z);
    return 0.5f * z * (1.0f + erfa);
}

// ---- LayerNorm + GELU over rows of 1024, one block per row
__global__ __launch_bounds__(256) void ln_gelu_kernel(const unsigned short* __restrict__ Y,
                                                      const float* __restrict__ g,
                                                      const float* __restrict__ b,
                                                      unsigned short* __restrict__ Aout){
    const int row = blockIdx.x;
    const int tid = threadIdx.x;
    const unsigned short* yr = Y + (size_t)row * Dm;
    ushort4 u = *(const ushort4*)(yr + tid * 4);
    float x0 = bf2f(u.x), x1 = bf2f(u.y), x2 = bf2f(u.z), x3 = bf2f(u.w);
    float s  = x0 + x1 + x2 + x3;
    float ss = x0 * x0 + x1 * x1 + x2 * x2 + x3 * x3;
    #pragma unroll
    for (int d = 32; d > 0; d >>= 1) {
        s  += __shfl_down(s, d);
        ss += __shfl_down(ss, d);
    }
    __shared__ float sb[8];
    const int wave = tid >> 6, lane = tid & 63;
    if (lane == 0) { sb[wave] = s; sb[4 + wave] = ss; }
    __syncthreads();
    s  = sb[0] + sb[1] + sb[2] + sb[3];
    ss = sb[4] + sb[5] + sb[6] + sb[7];
    const float mu = s * (1.0f / Dm);
    const float var = ss * (1.0f / Dm) - mu * mu;
    const float rstd = rsqrtf(var + 1e-5f);
    float4 gv = *(const float4*)(g + tid * 4);
    float4 bv = *(const float4*)(b + tid * 4);
    float z0 = (x0 - mu) * rstd * gv.x + bv.x;
    float z1 = (x1 - mu) * rstd * gv.y + bv.y;
    float z2 = (x2 - mu) * rstd * gv.z + bv.z;
    float z3 = (x3 - mu) * rstd * gv.w + bv.w;
    ushort4 o;
    o.x = f2bf(gelu_exact(z0)); o.y = f2bf(gelu_exact(z1));
    o.z = f2bf(gelu_exact(z2)); o.w = f2bf(gelu_exact(z3));
    *(ushort4*)(Aout + (size_t)row * Dm + tid * 4) = o;
}

extern "C" void kernel_launch(void* const* d_in, const int* in_sizes, int n_in,
                              void* d_out, int out_size, void* d_ws, size_t ws_size,
                              hipStream_t stream) {
    (void)in_sizes; (void)n_in; (void)out_size; (void)ws_size;
    const float* x   = (const float*)d_in[0];
    const int*   qw  = (const int*)d_in[1];
    const float* sc  = (const float*)d_in[2];
    const float* bia = (const float*)d_in[3];
    const float* la  = (const float*)d_in[4];
    const float* lb  = (const float*)d_in[5];
    const float* gam = (const float*)d_in[6];
    const float* bet = (const float*)d_in[7];
    float* out = (float*)d_out;

    char* p = (char*)d_ws;
    unsigned short* Wbf = (unsigned short*)p; p += (size_t)NLAYER * Dm * Dm * 2;
    unsigned short* Pb  = (unsigned short*)p; p += (size_t)MT * Dm * 2;
    unsigned short* Qb  = (unsigned short*)p; p += (size_t)MT * Dm * 2;

    prep_w2<<<NLAYER * Dm / 8, 256, 0, stream>>>(qw, sc, la, lb, Wbf);
    conv_bf16_kernel<<<MT * (Dm / 4) / 256, 256, 0, stream>>>(x, Pb);

    unsigned short *curP = Pb, *curQ = Qb;
    for (int blk = 0; blk < 3; blk++) {
        int i0 = 2 * blk, i1 = i0 + 1;
        qlora_gemm<<<512, 512, 0, stream>>>(
            curP, Wbf + (size_t)i0 * Dm * Dm,
            bia + i0 * Dm, nullptr, nullptr, curQ);
        ln_gelu_kernel<<<MT, 256, 0, stream>>>(curQ, gam + blk * Dm, bet + blk * Dm, curP);
        qlora_gemm<<<512, 512, 0, stream>>>(
            curP, Wbf + (size_t)i1 * Dm * Dm,
            bia + i1 * Dm, blk == 0 ? x : (const float*)out, out,
            blk == 2 ? nullptr : curQ);
        unsigned short* t = curP; curP = curQ; curQ = t;
    }
}